// Round 5
// baseline (125.268 us; speedup 1.0000x reference)
//
#include <hip/hip_runtime.h>

// AnatomicalConsistencyLoss: fused separable-Sobel magnitude + cosine loss.
// pred/target (2,1,160,160,160) f32 -> scalar f32.
// R5: (a) amdgpu_waves_per_eu(4,4) pins the backend's occupancy target so it
// stops spilling the z-ring to scratch (R2/R4 showed 8-29MB scratch writes);
// (b) float2 granularity halves the ring (36 VGPR) so everything fits in the
// 128-VGPR budget; (c) raw s_barrier + lgkmcnt(0)-only wait keeps prefetched
// global loads in flight across the barrier (true T14); (d) tile 32x16,
// grid 2000 for 2x TLP vs R2.

constexpr int Dd = 160, Hh = 160, Ww = 160;
constexpr int TW = 32, TH = 16, DC = 8;
constexpr int GRP = 16;                      // float2 groups per row
constexpr int ROWS = TH + 2;                 // 18
constexpr int NTX = Ww / TW;                 // 5
constexpr int NTY = Hh / TH;                 // 10
constexpr int NB_X = NTX * NTY;              // 50
constexpr int NB_Y = Dd / DC;                // 20
constexpr int NB_Z = 2;
constexpr int NBLOCKS = NB_X * NB_Y * NB_Z;  // 2000
constexpr int PLANES = DC + 2;               // 10
constexpr int PLSZ = Hh * Ww;                // 25600
constexpr double NVOX = 2.0 * Dd * Hh * Ww;  // 8,192,000

template <int N> struct IC { static constexpr int v = N; };

__device__ __forceinline__ float2 sm3f2(const float2 a, const float2 b, const float2 c) {
    return make_float2(a.x + 2.f*b.x + c.x, a.y + 2.f*b.y + c.y);
}
__device__ __forceinline__ float2 df2f2(const float2 a, const float2 c) {
    return make_float2(c.x - a.x, c.y - a.y);
}

__attribute__((amdgpu_waves_per_eu(4, 4)))
__global__ __launch_bounds__(256)
void acl_partial(const float* __restrict__ pred, const float* __restrict__ targ,
                 float2* __restrict__ partial)
{
    // [zbuf][vol][row][grp] float2; row stride 128B (0 conflicts measured R1-R4)
    __shared__ float2 sHS[2][2][ROWS][GRP];
    __shared__ float2 sHD[2][2][ROWS][GRP];
    __shared__ float rred[8];

    const int tid = threadIdx.x;
    const int gx = tid & 15;          // x-group of 2 floats
    const int r  = tid >> 4;          // row 0..15

    const int wt = blockIdx.x % NTX;
    const int ht = blockIdx.x / NTX;
    const int x0 = wt * TW, y0 = ht * TH;
    const int z0 = blockIdx.y * DC;
    const size_t base = (size_t)blockIdx.z * ((size_t)Dd * PLSZ);
    const float* __restrict__ pv = pred + base;
    const float* __restrict__ tv = targ + base;

    const int X = x0 + 2 * gx;
    const bool eLo = (gx == 0);
    const bool eHi = (gx == 15);
    const bool xm  = (x0 > 0);
    const bool xp  = (x0 + TW < Ww);

    // primary row slot (rows 0..15)
    const int gy1   = y0 - 1 + r;
    const bool yok1 = (unsigned)gy1 < (unsigned)Hh;
    const int o1    = gy1 * Ww + X;
    // secondary row slots (rows 16,17 via tid<32)
    const bool has2 = (tid < 32);
    const int r2    = TH + (tid >> 4);          // 16/17 for tid<32
    const int gy2   = y0 - 1 + r2;
    const bool yok2 = has2 && ((unsigned)gy2 < (unsigned)Hh);
    const int o2    = gy2 * Ww + X;

    // prefetch registers (one plane in flight; small live set: 16 dwords)
    float2 vAp, vAt, vBp, vBt;
    float eA0p, eA1p, eA0t, eA1t, eB0p, eB1p, eB0t, eB1t;

    auto issue = [&](int p) {
        const int gz = z0 - 1 + p;
        const bool zok = (unsigned)gz < (unsigned)Dd;   // wave-uniform
        const float* pz = pv + (ptrdiff_t)gz * PLSZ;
        const float* tz = tv + (ptrdiff_t)gz * PLSZ;
        vAp = vAt = vBp = vBt = make_float2(0.f, 0.f);
        eA0p = eA1p = eA0t = eA1t = 0.f;
        eB0p = eB1p = eB0t = eB1t = 0.f;
        if (zok) {
            if (yok1) {
                vAp = *(const float2*)(pz + o1);
                vAt = *(const float2*)(tz + o1);
                if (eLo && xm) { eA0p = pz[o1 - 1]; eA0t = tz[o1 - 1]; }
                if (eHi && xp) { eA1p = pz[o1 + 2]; eA1t = tz[o1 + 2]; }
            }
            if (yok2) {
                vBp = *(const float2*)(pz + o2);
                vBt = *(const float2*)(tz + o2);
                if (eLo && xm) { eB0p = pz[o2 - 1]; eB0t = tz[o2 - 1]; }
                if (eHi && xp) { eB1p = pz[o2 + 2]; eB1t = tz[o2 + 2]; }
            }
        }
    };

    // horizontal combos; x-halo via shfl (all 64 lanes execute; edge lanes and
    // row-crossing lanes overridden with their prefetched scalar)
    auto combo = [&](const float2 v, const float el, const float er,
                     float2& HS, float2& HD) {
        float e0 = __shfl_up(v.y, 1);
        if (eLo) e0 = el;
        float e2 = __shfl_down(v.x, 1);
        if (eHi) e2 = er;
        HS = make_float2(e0 + 2.f*v.x + v.y, v.x + 2.f*v.y + e2);
        HD = make_float2(v.y - e0, e2 - v.x);
    };

    float2 Ap[3], Bp[3], Cp[3], At[3], Bt[3], Ct[3];
    float2 accm = make_float2(0.f, 0.f);
    float2 accc = make_float2(0.f, 0.f);

    issue(0);

    auto step = [&](auto Pc) {
        constexpr int P   = decltype(Pc)::v;
        constexpr int BUF = P & 1;
        constexpr int S2  = P % 3;

        // ---- consume prefetch -> combos -> LDS[BUF] ----
        {
            float2 hs, hd;
            combo(vAp, eA0p, eA1p, hs, hd);
            sHS[BUF][0][r][gx] = hs;  sHD[BUF][0][r][gx] = hd;
            combo(vAt, eA0t, eA1t, hs, hd);
            sHS[BUF][1][r][gx] = hs;  sHD[BUF][1][r][gx] = hd;

            float2 h2p, d2p, h2t, d2t;                 // all lanes (shfl), write masked
            combo(vBp, eB0p, eB1p, h2p, d2p);
            combo(vBt, eB0t, eB1t, h2t, d2t);
            if (has2) {
                sHS[BUF][0][r2][gx] = h2p;  sHD[BUF][0][r2][gx] = d2p;
                sHS[BUF][1][r2][gx] = h2t;  sHD[BUF][1][r2][gx] = d2t;
            }
        }

        // ---- issue next plane's loads: they stay in flight across s_barrier
        // (lgkm-only wait below; raw s_barrier does NOT drain vmcnt) ----
        if constexpr (P + 1 < PLANES) { issue(P + 1); }

        asm volatile("s_waitcnt lgkmcnt(0)" ::: "memory");   // LDS writes visible
        __builtin_amdgcn_s_barrier();

        // ---- vertical combine into static ring slot ----
        {
            const float2 h0 = sHS[BUF][0][r][gx], h1 = sHS[BUF][0][r+1][gx], h2 = sHS[BUF][0][r+2][gx];
            const float2 d0 = sHD[BUF][0][r][gx], d1 = sHD[BUF][0][r+1][gx], d2 = sHD[BUF][0][r+2][gx];
            Ap[S2] = sm3f2(h0, h1, h2);
            Cp[S2] = df2f2(h0, h2);
            Bp[S2] = sm3f2(d0, d1, d2);
        }
        {
            const float2 h0 = sHS[BUF][1][r][gx], h1 = sHS[BUF][1][r+1][gx], h2 = sHS[BUF][1][r+2][gx];
            const float2 d0 = sHD[BUF][1][r][gx], d1 = sHD[BUF][1][r+1][gx], d2 = sHD[BUF][1][r+2][gx];
            At[S2] = sm3f2(h0, h1, h2);
            Ct[S2] = df2f2(h0, h2);
            Bt[S2] = sm3f2(d0, d1, d2);
        }

        if constexpr (P >= 2) {
            constexpr int S0 = (P - 2) % 3, S1 = (P - 1) % 3;
            const float2 gxp = sm3f2(Bp[S0], Bp[S1], Bp[S2]);
            const float2 gyp = sm3f2(Cp[S0], Cp[S1], Cp[S2]);
            const float2 gzp = df2f2(Ap[S0], Ap[S2]);
            const float2 gxt = sm3f2(Bt[S0], Bt[S1], Bt[S2]);
            const float2 gyt = sm3f2(Ct[S0], Ct[S1], Ct[S2]);
            const float2 gzt = df2f2(At[S0], At[S2]);

            #define LOSS_COMP(c)                                                  \
            {                                                                     \
                const float np2 = gxp.c*gxp.c + gyp.c*gyp.c + gzp.c*gzp.c;        \
                const float nt2 = gxt.c*gxt.c + gyt.c*gyt.c + gzt.c*gzt.c;        \
                const float pm = __builtin_amdgcn_sqrtf(np2 + 1e-8f);             \
                const float tm = __builtin_amdgcn_sqrtf(nt2 + 1e-8f);             \
                const float dm = pm - tm;                                         \
                accm.c += dm * dm;                                                \
                const float dt = gxp.c*gxt.c + gyp.c*gyt.c + gzp.c*gzt.c;         \
                const float ra = __builtin_amdgcn_rsqf(fmaxf(np2, 1e-30f));       \
                const float rb = __builtin_amdgcn_rsqf(fmaxf(nt2, 1e-30f));       \
                accc.c += dt * ra * rb;                                           \
            }
            LOSS_COMP(x)
            LOSS_COMP(y)
            #undef LOSS_COMP
        }
        // single barrier per plane: next step writes the OTHER buffer; reuse of
        // this buffer (step P+2) is ordered by step P+1's barrier.
    };

    step(IC<0>{}); step(IC<1>{}); step(IC<2>{}); step(IC<3>{}); step(IC<4>{});
    step(IC<5>{}); step(IC<6>{}); step(IC<7>{}); step(IC<8>{}); step(IC<9>{});

    // ---- block reduction ----
    float am = accm.x + accm.y;
    float ac = accc.x + accc.y;
    #pragma unroll
    for (int off = 32; off >= 1; off >>= 1) {
        am += __shfl_down(am, off);
        ac += __shfl_down(ac, off);
    }
    const int wid = tid >> 6;
    if ((tid & 63) == 0) { rred[wid] = am; rred[4 + wid] = ac; }
    __syncthreads();
    if (tid == 0) {
        const float m = rred[0] + rred[1] + rred[2] + rred[3];
        const float c = rred[4] + rred[5] + rred[6] + rred[7];
        const int bid = (blockIdx.z * gridDim.y + blockIdx.y) * gridDim.x + blockIdx.x;
        partial[bid] = make_float2(m, c);
    }
}

__global__ __launch_bounds__(256)
void acl_final(const float2* __restrict__ partial, float* __restrict__ out)
{
    __shared__ double sm[256], sc[256];
    double m = 0.0, c = 0.0;
    for (int i = threadIdx.x; i < NBLOCKS; i += 256) {
        const float2 v = partial[i];
        m += (double)v.x;
        c += (double)v.y;
    }
    sm[threadIdx.x] = m;
    sc[threadIdx.x] = c;
    __syncthreads();
    #pragma unroll
    for (int s = 128; s >= 1; s >>= 1) {
        if (threadIdx.x < (unsigned)s) {
            sm[threadIdx.x] += sm[threadIdx.x + s];
            sc[threadIdx.x] += sc[threadIdx.x + s];
        }
        __syncthreads();
    }
    if (threadIdx.x == 0) {
        const double mag_loss = sm[0] / NVOX;
        const double dir_loss = 1.0 - sc[0] / NVOX;
        out[0] = (float)(0.2 * (mag_loss + dir_loss));
    }
}

extern "C" void kernel_launch(void* const* d_in, const int* in_sizes, int n_in,
                              void* d_out, int out_size, void* d_ws, size_t ws_size,
                              hipStream_t stream) {
    const float* pred = (const float*)d_in[0];
    const float* targ = (const float*)d_in[1];
    float* out = (float*)d_out;
    float2* partial = (float2*)d_ws;  // 2000 * 8 B = 16 KB

    dim3 grid(NB_X, NB_Y, NB_Z);  // (50, 20, 2)
    acl_partial<<<grid, 256, 0, stream>>>(pred, targ, partial);
    acl_final<<<1, 256, 0, stream>>>(partial, out);
}

// Round 6
// 48.479 us; speedup vs baseline: 2.5840x; 2.5840x over previous
//
#include <hip/hip_runtime.h>

// AnatomicalConsistencyLoss: fused separable-Sobel magnitude + cosine loss.
// pred/target (2,1,160,160,160) f32 -> scalar f32.
// R6: kill the register z-ring (the backend spilled it in R2-R5: it caps VGPRs
// at 64-84 for occupancy and dumps the rest to scratch). Streaming pending-sum
// formulation: per plane, finalize output p-2, shift two pending partial
// gradients. Persistent state = 28 dwords of NAMED scalars (no arrays, no
// lambdas, rolled loop). Latency hidden by TLP: 9.3KB LDS, 2000 blocks,
// ~8 blocks/CU. Two barriers/plane, single LDS combo buffer.

constexpr int Dd = 160, Hh = 160, Ww = 160;
constexpr int TW = 32, TH = 16, DC = 8;
constexpr int GRP = 16;                      // float2 groups per row
constexpr int ROWS = TH + 2;                 // 18
constexpr int NTX = Ww / TW;                 // 5
constexpr int NTY = Hh / TH;                 // 10
constexpr int NB_X = NTX * NTY;              // 50
constexpr int NB_Y = Dd / DC;                // 20
constexpr int NB_Z = 2;
constexpr int NBLOCKS = NB_X * NB_Y * NB_Z;  // 2000
constexpr int PLANES = DC + 2;               // 10
constexpr int PLSZ = Hh * Ww;                // 25600
constexpr double NVOX = 2.0 * Dd * Hh * Ww;  // 8,192,000

__device__ __forceinline__ float2 sm3f2(const float2 a, const float2 b, const float2 c) {
    return make_float2(a.x + 2.f*b.x + c.x, a.y + 2.f*b.y + c.y);
}
__device__ __forceinline__ float2 df2f2(const float2 a, const float2 c) {
    return make_float2(c.x - a.x, c.y - a.y);
}
__device__ __forceinline__ float2 add2(const float2 a, const float2 b) {
    return make_float2(a.x + b.x, a.y + b.y);
}
__device__ __forceinline__ float2 fma2s(const float2 a, const float s, const float2 b) {
    return make_float2(fmaf(a.x, s, b.x), fmaf(a.y, s, b.y));
}
__device__ __forceinline__ float2 neg2(const float2 a) {
    return make_float2(-a.x, -a.y);
}

// horizontal 1D combos from a float2 + left/right halo via lane shuffle
__device__ __forceinline__ void combo2(const float2 v, const float el, const float er,
                                       const bool eLo, const bool eHi,
                                       float2& HS, float2& HD) {
    float e0 = __shfl_up(v.y, 1);
    if (eLo) e0 = el;
    float e2 = __shfl_down(v.x, 1);
    if (eHi) e2 = er;
    HS = make_float2(e0 + 2.f*v.x + v.y, v.x + 2.f*v.y + e2);
    HD = make_float2(v.y - e0, e2 - v.x);
}

__global__ __launch_bounds__(256)
void acl_partial(const float* __restrict__ pred, const float* __restrict__ targ,
                 float2* __restrict__ partial)
{
    // [vol][row][grp] float2; row stride 128B (0 bank conflicts measured R1-R5)
    __shared__ float2 sHS[2][ROWS][GRP];
    __shared__ float2 sHD[2][ROWS][GRP];
    __shared__ float rred[8];

    const int tid = threadIdx.x;
    const int gx = tid & 15;          // x-group of 2 floats
    const int r  = tid >> 4;          // row 0..15

    const int wt = blockIdx.x % NTX;
    const int ht = blockIdx.x / NTX;
    const int x0 = wt * TW, y0 = ht * TH;
    const int z0 = blockIdx.y * DC;
    const size_t base = (size_t)blockIdx.z * ((size_t)Dd * PLSZ);
    const float* __restrict__ pv = pred + base;
    const float* __restrict__ tv = targ + base;

    const int X = x0 + 2 * gx;
    const bool eLo = (gx == 0);
    const bool eHi = (gx == 15);
    const bool xm  = (x0 > 0);
    const bool xp  = (x0 + TW < Ww);

    // primary row (0..15) and secondary rows (16,17 handled by tid<32)
    const int gy1   = y0 - 1 + r;
    const bool yok1 = (unsigned)gy1 < (unsigned)Hh;
    const int o1    = gy1 * Ww + X;
    const bool has2 = (tid < 32);
    const int r2    = TH + (tid >> 4);           // 16/17 for tid<32
    const int gy2   = y0 - 1 + r2;
    const bool yok2 = has2 && ((unsigned)gy2 < (unsigned)Hh);
    const int o2    = gy2 * Ww + X;

    const float2 z2 = make_float2(0.f, 0.f);

    // pending partial gradients for the next two output planes (named scalars,
    // NO arrays -> nothing the allocator can dump to scratch wholesale)
    float2 P1x = z2, P1y = z2, P1z = z2, P2x = z2, P2y = z2, P2z = z2;  // pred
    float2 T1x = z2, T1y = z2, T1z = z2, T2x = z2, T2y = z2, T2z = z2;  // targ
    float2 accm = z2, accc = z2;

    for (int p = 0; p < PLANES; ++p) {
        const int gz = z0 - 1 + p;
        const bool zok = (unsigned)gz < (unsigned)Dd;   // wave-uniform
        const float* pz = pv + (ptrdiff_t)gz * PLSZ;
        const float* tz = tv + (ptrdiff_t)gz * PLSZ;

        // ---- global loads for this plane (issued before barrier #1 so other
        //      waves' compute hides them) ----
        float2 vAp = z2, vAt = z2, vBp = z2, vBt = z2;
        float eA0p = 0.f, eA1p = 0.f, eA0t = 0.f, eA1t = 0.f;
        float eB0p = 0.f, eB1p = 0.f, eB0t = 0.f, eB1t = 0.f;
        if (zok && yok1) {
            vAp = *(const float2*)(pz + o1);
            vAt = *(const float2*)(tz + o1);
            if (eLo && xm) { eA0p = pz[o1 - 1]; eA0t = tz[o1 - 1]; }
            if (eHi && xp) { eA1p = pz[o1 + 2]; eA1t = tz[o1 + 2]; }
        }
        if (zok && yok2) {
            vBp = *(const float2*)(pz + o2);
            vBt = *(const float2*)(tz + o2);
            if (eLo && xm) { eB0p = pz[o2 - 1]; eB0t = tz[o2 - 1]; }
            if (eHi && xp) { eB1p = pz[o2 + 2]; eB1t = tz[o2 + 2]; }
        }

        __syncthreads();   // previous plane's LDS reads complete

        // ---- stage A: horizontal combos -> LDS ----
        {
            float2 hs, hd;
            combo2(vAp, eA0p, eA1p, eLo, eHi, hs, hd);
            sHS[0][r][gx] = hs;  sHD[0][r][gx] = hd;
            combo2(vAt, eA0t, eA1t, eLo, eHi, hs, hd);
            sHS[1][r][gx] = hs;  sHD[1][r][gx] = hd;
        }
        if (tid < 64) {        // wave-uniform: only wave 0 (shfl stays inside it)
            float2 hp, dp, htt, dtt;
            combo2(vBp, eB0p, eB1p, eLo, eHi, hp, dp);
            combo2(vBt, eB0t, eB1t, eLo, eHi, htt, dtt);
            if (has2) {
                sHS[0][r2][gx] = hp;   sHD[0][r2][gx] = dp;
                sHS[1][r2][gx] = htt;  sHD[1][r2][gx] = dtt;
            }
        }

        __syncthreads();   // combos visible

        // ---- stage B: vertical combine + streaming pending update ----
        float2 fpx, fpy, fpz, ftx, fty, ftz;
        {
            const float2 h0 = sHS[0][r][gx], h1 = sHS[0][r+1][gx], h2 = sHS[0][r+2][gx];
            const float2 d0 = sHD[0][r][gx], d1 = sHD[0][r+1][gx], d2 = sHD[0][r+2][gx];
            const float2 A = sm3f2(h0, h1, h2);   // sm_y(sm_x) -> z-deriv path
            const float2 B = sm3f2(d0, d1, d2);   // sm_y(d_x)  -> x-gradient path
            const float2 C = df2f2(h0, h2);       // d_y(sm_x)  -> y-gradient path
            fpx = add2(P1x, B);  fpy = add2(P1y, C);  fpz = add2(P1z, A);
            P1x = fma2s(B, 2.f, P2x);  P1y = fma2s(C, 2.f, P2y);  P1z = P2z;
            P2x = B;  P2y = C;  P2z = neg2(A);
        }
        {
            const float2 h0 = sHS[1][r][gx], h1 = sHS[1][r+1][gx], h2 = sHS[1][r+2][gx];
            const float2 d0 = sHD[1][r][gx], d1 = sHD[1][r+1][gx], d2 = sHD[1][r+2][gx];
            const float2 A = sm3f2(h0, h1, h2);
            const float2 B = sm3f2(d0, d1, d2);
            const float2 C = df2f2(h0, h2);
            ftx = add2(T1x, B);  fty = add2(T1y, C);  ftz = add2(T1z, A);
            T1x = fma2s(B, 2.f, T2x);  T1y = fma2s(C, 2.f, T2y);  T1z = T2z;
            T2x = B;  T2y = C;  T2z = neg2(A);
        }

        if (p >= 2) {   // output plane z0 + (p-2) is finalized
            #define LOSS_COMP(c)                                                  \
            {                                                                     \
                const float np2 = fpx.c*fpx.c + fpy.c*fpy.c + fpz.c*fpz.c;        \
                const float nt2 = ftx.c*ftx.c + fty.c*fty.c + ftz.c*ftz.c;        \
                const float pm = __builtin_amdgcn_sqrtf(np2 + 1e-8f);             \
                const float tm = __builtin_amdgcn_sqrtf(nt2 + 1e-8f);             \
                const float dm = pm - tm;                                         \
                accm.c += dm * dm;                                                \
                const float dt = fpx.c*ftx.c + fpy.c*fty.c + fpz.c*ftz.c;         \
                const float ra = __builtin_amdgcn_rsqf(fmaxf(np2, 1e-30f));       \
                const float rb = __builtin_amdgcn_rsqf(fmaxf(nt2, 1e-30f));       \
                accc.c += dt * ra * rb;                                           \
            }
            LOSS_COMP(x)
            LOSS_COMP(y)
            #undef LOSS_COMP
        }
    }

    // ---- block reduction ----
    float am = accm.x + accm.y;
    float ac = accc.x + accc.y;
    #pragma unroll
    for (int off = 32; off >= 1; off >>= 1) {
        am += __shfl_down(am, off);
        ac += __shfl_down(ac, off);
    }
    const int wid = tid >> 6;
    if ((tid & 63) == 0) { rred[wid] = am; rred[4 + wid] = ac; }
    __syncthreads();
    if (tid == 0) {
        const float m = rred[0] + rred[1] + rred[2] + rred[3];
        const float c = rred[4] + rred[5] + rred[6] + rred[7];
        const int bid = (blockIdx.z * gridDim.y + blockIdx.y) * gridDim.x + blockIdx.x;
        partial[bid] = make_float2(m, c);
    }
}

__global__ __launch_bounds__(256)
void acl_final(const float2* __restrict__ partial, float* __restrict__ out)
{
    __shared__ double sm[256], sc[256];
    double m = 0.0, c = 0.0;
    for (int i = threadIdx.x; i < NBLOCKS; i += 256) {
        const float2 v = partial[i];
        m += (double)v.x;
        c += (double)v.y;
    }
    sm[threadIdx.x] = m;
    sc[threadIdx.x] = c;
    __syncthreads();
    #pragma unroll
    for (int s = 128; s >= 1; s >>= 1) {
        if (threadIdx.x < (unsigned)s) {
            sm[threadIdx.x] += sm[threadIdx.x + s];
            sc[threadIdx.x] += sc[threadIdx.x + s];
        }
        __syncthreads();
    }
    if (threadIdx.x == 0) {
        const double mag_loss = sm[0] / NVOX;
        const double dir_loss = 1.0 - sc[0] / NVOX;
        out[0] = (float)(0.2 * (mag_loss + dir_loss));
    }
}

extern "C" void kernel_launch(void* const* d_in, const int* in_sizes, int n_in,
                              void* d_out, int out_size, void* d_ws, size_t ws_size,
                              hipStream_t stream) {
    const float* pred = (const float*)d_in[0];
    const float* targ = (const float*)d_in[1];
    float* out = (float*)d_out;
    float2* partial = (float2*)d_ws;  // 2000 * 8 B = 16 KB

    dim3 grid(NB_X, NB_Y, NB_Z);  // (50, 20, 2)
    acl_partial<<<grid, 256, 0, stream>>>(pred, targ, partial);
    acl_final<<<1, 256, 0, stream>>>(partial, out);
}

// Round 7
// 44.917 us; speedup vs baseline: 2.7889x; 1.0793x over previous
//
#include <hip/hip_runtime.h>

// AnatomicalConsistencyLoss: fused separable-Sobel magnitude + cosine loss.
// pred/target (2,1,160,160,160) f32 -> scalar f32.
// R7 = R6 (streaming pending-sum, 28-dword state, no spills) + the R5 pipeline
// that R6's small state now makes safe: 1-plane register prefetch consumed at
// iteration top, single raw s_barrier per plane with lgkmcnt-only drain
// (global loads stay in flight across the barrier), double-buffered combo LDS.

constexpr int Dd = 160, Hh = 160, Ww = 160;
constexpr int TW = 32, TH = 16, DC = 8;
constexpr int GRP = 16;                      // float2 groups per row
constexpr int ROWS = TH + 2;                 // 18
constexpr int NTX = Ww / TW;                 // 5
constexpr int NTY = Hh / TH;                 // 10
constexpr int NB_X = NTX * NTY;              // 50
constexpr int NB_Y = Dd / DC;                // 20
constexpr int NB_Z = 2;
constexpr int NBLOCKS = NB_X * NB_Y * NB_Z;  // 2000
constexpr int PLANES = DC + 2;               // 10
constexpr int PLSZ = Hh * Ww;                // 25600
constexpr double NVOX = 2.0 * Dd * Hh * Ww;  // 8,192,000

__device__ __forceinline__ float2 sm3f2(const float2 a, const float2 b, const float2 c) {
    return make_float2(a.x + 2.f*b.x + c.x, a.y + 2.f*b.y + c.y);
}
__device__ __forceinline__ float2 df2f2(const float2 a, const float2 c) {
    return make_float2(c.x - a.x, c.y - a.y);
}
__device__ __forceinline__ float2 add2(const float2 a, const float2 b) {
    return make_float2(a.x + b.x, a.y + b.y);
}
__device__ __forceinline__ float2 fma2s(const float2 a, const float s, const float2 b) {
    return make_float2(fmaf(a.x, s, b.x), fmaf(a.y, s, b.y));
}
__device__ __forceinline__ float2 neg2(const float2 a) {
    return make_float2(-a.x, -a.y);
}

// horizontal 1D combos from a float2 + left/right halo via lane shuffle
__device__ __forceinline__ void combo2(const float2 v, const float el, const float er,
                                       const bool eLo, const bool eHi,
                                       float2& HS, float2& HD) {
    float e0 = __shfl_up(v.y, 1);
    if (eLo) e0 = el;
    float e2 = __shfl_down(v.x, 1);
    if (eHi) e2 = er;
    HS = make_float2(e0 + 2.f*v.x + v.y, v.x + 2.f*v.y + e2);
    HD = make_float2(v.y - e0, e2 - v.x);
}

__global__ __launch_bounds__(256)
void acl_partial(const float* __restrict__ pred, const float* __restrict__ targ,
                 float2* __restrict__ partial)
{
    // [zbuf][vol][row][grp] float2; row stride 128B (0 bank conflicts R1-R6)
    __shared__ float2 sHS[2][2][ROWS][GRP];
    __shared__ float2 sHD[2][2][ROWS][GRP];
    __shared__ float rred[8];

    const int tid = threadIdx.x;
    const int gx = tid & 15;          // x-group of 2 floats
    const int r  = tid >> 4;          // row 0..15

    const int wt = blockIdx.x % NTX;
    const int ht = blockIdx.x / NTX;
    const int x0 = wt * TW, y0 = ht * TH;
    const int z0 = blockIdx.y * DC;
    const size_t base = (size_t)blockIdx.z * ((size_t)Dd * PLSZ);
    const float* __restrict__ pv = pred + base;
    const float* __restrict__ tv = targ + base;

    const int X = x0 + 2 * gx;
    const bool eLo = (gx == 0);
    const bool eHi = (gx == 15);
    const bool xm  = (x0 > 0);
    const bool xp  = (x0 + TW < Ww);

    // primary row (0..15); secondary rows 16,17 handled by tid<32 (wave 0)
    const int gy1   = y0 - 1 + r;
    const bool yok1 = (unsigned)gy1 < (unsigned)Hh;
    const int o1    = gy1 * Ww + X;
    const bool has2 = (tid < 32);
    const int r2    = TH + (tid >> 4);           // 16/17 for tid<32
    const int gy2   = y0 - 1 + r2;
    const bool yok2 = has2 && ((unsigned)gy2 < (unsigned)Hh);
    const int o2    = gy2 * Ww + X;

    const float2 z2 = make_float2(0.f, 0.f);

    // streaming pending partial gradients (named scalars only)
    float2 P1x = z2, P1y = z2, P1z = z2, P2x = z2, P2y = z2, P2z = z2;  // pred
    float2 T1x = z2, T1y = z2, T1z = z2, T2x = z2, T2y = z2, T2z = z2;  // targ
    float2 accm = z2, accc = z2;

    // prefetch registers: one plane in flight (16 dwords)
    float2 vAp = z2, vAt = z2, vBp = z2, vBt = z2;
    float eA0p = 0.f, eA1p = 0.f, eA0t = 0.f, eA1t = 0.f;
    float eB0p = 0.f, eB1p = 0.f, eB0t = 0.f, eB1t = 0.f;

    auto issue = [&](int p) {
        const int gz = z0 - 1 + p;
        const bool zok = (unsigned)gz < (unsigned)Dd;   // wave-uniform
        const float* pz = pv + (ptrdiff_t)gz * PLSZ;
        const float* tz = tv + (ptrdiff_t)gz * PLSZ;
        vAp = vAt = vBp = vBt = z2;
        eA0p = eA1p = eA0t = eA1t = 0.f;
        eB0p = eB1p = eB0t = eB1t = 0.f;
        if (zok && yok1) {
            vAp = *(const float2*)(pz + o1);
            vAt = *(const float2*)(tz + o1);
            if (eLo && xm) { eA0p = pz[o1 - 1]; eA0t = tz[o1 - 1]; }
            if (eHi && xp) { eA1p = pz[o1 + 2]; eA1t = tz[o1 + 2]; }
        }
        if (zok && yok2) {
            vBp = *(const float2*)(pz + o2);
            vBt = *(const float2*)(tz + o2);
            if (eLo && xm) { eB0p = pz[o2 - 1]; eB0t = tz[o2 - 1]; }
            if (eHi && xp) { eB1p = pz[o2 + 2]; eB1t = tz[o2 + 2]; }
        }
    };

    issue(0);

    for (int p = 0; p < PLANES; ++p) {
        const int buf = p & 1;

        // ---- stage A: consume prefetch -> horizontal combos -> LDS[buf] ----
        {
            float2 hs, hd;
            combo2(vAp, eA0p, eA1p, eLo, eHi, hs, hd);
            sHS[buf][0][r][gx] = hs;  sHD[buf][0][r][gx] = hd;
            combo2(vAt, eA0t, eA1t, eLo, eHi, hs, hd);
            sHS[buf][1][r][gx] = hs;  sHD[buf][1][r][gx] = hd;
        }
        if (tid < 64) {        // wave-uniform: shfl stays inside wave 0
            float2 hp, dp, htt, dtt;
            combo2(vBp, eB0p, eB1p, eLo, eHi, hp, dp);
            combo2(vBt, eB0t, eB1t, eLo, eHi, htt, dtt);
            if (has2) {
                sHS[buf][0][r2][gx] = hp;   sHD[buf][0][r2][gx] = dp;
                sHS[buf][1][r2][gx] = htt;  sHD[buf][1][r2][gx] = dtt;
            }
        }

        // ---- issue next plane's loads: they stay in flight across the
        //      barrier (lgkm-only drain below; raw s_barrier keeps vmcnt) ----
        if (p + 1 < PLANES) issue(p + 1);

        asm volatile("s_waitcnt lgkmcnt(0)" ::: "memory");   // ds_writes done
        __builtin_amdgcn_s_barrier();
        asm volatile("" ::: "memory");                       // no read hoisting

        // ---- stage B: vertical combine + streaming pending update ----
        float2 fpx, fpy, fpz, ftx, fty, ftz;
        {
            const float2 h0 = sHS[buf][0][r][gx], h1 = sHS[buf][0][r+1][gx], h2 = sHS[buf][0][r+2][gx];
            const float2 d0 = sHD[buf][0][r][gx], d1 = sHD[buf][0][r+1][gx], d2 = sHD[buf][0][r+2][gx];
            const float2 A = sm3f2(h0, h1, h2);   // sm_y(sm_x) -> z-deriv path
            const float2 B = sm3f2(d0, d1, d2);   // sm_y(d_x)  -> x-gradient
            const float2 C = df2f2(h0, h2);       // d_y(sm_x)  -> y-gradient
            fpx = add2(P1x, B);  fpy = add2(P1y, C);  fpz = add2(P1z, A);
            P1x = fma2s(B, 2.f, P2x);  P1y = fma2s(C, 2.f, P2y);  P1z = P2z;
            P2x = B;  P2y = C;  P2z = neg2(A);
        }
        {
            const float2 h0 = sHS[buf][1][r][gx], h1 = sHS[buf][1][r+1][gx], h2 = sHS[buf][1][r+2][gx];
            const float2 d0 = sHD[buf][1][r][gx], d1 = sHD[buf][1][r+1][gx], d2 = sHD[buf][1][r+2][gx];
            const float2 A = sm3f2(h0, h1, h2);
            const float2 B = sm3f2(d0, d1, d2);
            const float2 C = df2f2(h0, h2);
            ftx = add2(T1x, B);  fty = add2(T1y, C);  ftz = add2(T1z, A);
            T1x = fma2s(B, 2.f, T2x);  T1y = fma2s(C, 2.f, T2y);  T1z = T2z;
            T2x = B;  T2y = C;  T2z = neg2(A);
        }

        if (p >= 2) {   // output plane z0 + (p-2) finalized
            #define LOSS_COMP(c)                                                  \
            {                                                                     \
                const float np2 = fpx.c*fpx.c + fpy.c*fpy.c + fpz.c*fpz.c;        \
                const float nt2 = ftx.c*ftx.c + fty.c*fty.c + ftz.c*ftz.c;        \
                const float pm = __builtin_amdgcn_sqrtf(np2 + 1e-8f);             \
                const float tm = __builtin_amdgcn_sqrtf(nt2 + 1e-8f);             \
                const float dm = pm - tm;                                         \
                accm.c += dm * dm;                                                \
                const float dt = fpx.c*ftx.c + fpy.c*fty.c + fpz.c*ftz.c;         \
                const float ra = __builtin_amdgcn_rsqf(fmaxf(np2, 1e-30f));       \
                const float rb = __builtin_amdgcn_rsqf(fmaxf(nt2, 1e-30f));       \
                accc.c += dt * ra * rb;                                           \
            }
            LOSS_COMP(x)
            LOSS_COMP(y)
            #undef LOSS_COMP
        }
        // single barrier/plane: next iter writes the OTHER buffer; reuse of
        // this one (iter p+2, after barrier p+1) cannot race reads before it.
    }

    // ---- block reduction ----
    float am = accm.x + accm.y;
    float ac = accc.x + accc.y;
    #pragma unroll
    for (int off = 32; off >= 1; off >>= 1) {
        am += __shfl_down(am, off);
        ac += __shfl_down(ac, off);
    }
    const int wid = tid >> 6;
    if ((tid & 63) == 0) { rred[wid] = am; rred[4 + wid] = ac; }
    __syncthreads();
    if (tid == 0) {
        const float m = rred[0] + rred[1] + rred[2] + rred[3];
        const float c = rred[4] + rred[5] + rred[6] + rred[7];
        const int bid = (blockIdx.z * gridDim.y + blockIdx.y) * gridDim.x + blockIdx.x;
        partial[bid] = make_float2(m, c);
    }
}

__global__ __launch_bounds__(256)
void acl_final(const float2* __restrict__ partial, float* __restrict__ out)
{
    __shared__ double sm[256], sc[256];
    double m = 0.0, c = 0.0;
    for (int i = threadIdx.x; i < NBLOCKS; i += 256) {
        const float2 v = partial[i];
        m += (double)v.x;
        c += (double)v.y;
    }
    sm[threadIdx.x] = m;
    sc[threadIdx.x] = c;
    __syncthreads();
    #pragma unroll
    for (int s = 128; s >= 1; s >>= 1) {
        if (threadIdx.x < (unsigned)s) {
            sm[threadIdx.x] += sm[threadIdx.x + s];
            sc[threadIdx.x] += sc[threadIdx.x + s];
        }
        __syncthreads();
    }
    if (threadIdx.x == 0) {
        const double mag_loss = sm[0] / NVOX;
        const double dir_loss = 1.0 - sc[0] / NVOX;
        out[0] = (float)(0.2 * (mag_loss + dir_loss));
    }
}

extern "C" void kernel_launch(void* const* d_in, const int* in_sizes, int n_in,
                              void* d_out, int out_size, void* d_ws, size_t ws_size,
                              hipStream_t stream) {
    const float* pred = (const float*)d_in[0];
    const float* targ = (const float*)d_in[1];
    float* out = (float*)d_out;
    float2* partial = (float2*)d_ws;  // 2000 * 8 B = 16 KB

    dim3 grid(NB_X, NB_Y, NB_Z);  // (50, 20, 2)
    acl_partial<<<grid, 256, 0, stream>>>(pred, targ, partial);
    acl_final<<<1, 256, 0, stream>>>(partial, out);
}